// Round 2
// baseline (40767.593 us; speedup 1.0000x reference)
//
#include <hip/hip_runtime.h>

#define NATOMS 300000
#define NCOLS 8
#define VOCABSZ 4096
#define DCOL 32
#define HIDDIM 256
#define NBONDS 320000
#define NGRAPHS 6000
#define NSTEPS 3

constexpr int MP = 300032;            // atoms padded to multiple of 64
constexpr int GEMM_BLOCKS = MP / 64;  // 4688

// ---------------------------------------------------------------------------
// Global scratch pool, allocated ONCE at shared-library load time (dlopen),
// i.e. outside kernel_launch and outside any graph capture. kernel_launch
// performs identical work every call against this fixed pool.
static void* g_pool = nullptr;
__attribute__((constructor)) static void alloc_pool() {
    void* p = nullptr;
    if (hipMalloc(&p, (size_t)960 * 1024 * 1024) == hipSuccess) g_pool = p;
}

// ---------------------------------------------------------------------------
__global__ void fill_kernel(float* out, float v, int n) {
    int i = blockIdx.x * blockDim.x + threadIdx.x;
    if (i < n) out[i] = v;
}

// ---------------------------------------------------------------------------
// Build per-dst linked lists of directed edges (src = concat(u,v), dst = concat(v,u))
__global__ void build_edges_kernel(const int* __restrict__ bf, int* __restrict__ esrc,
                                   int* __restrict__ nxt, int* head) {
    int e = blockIdx.x * blockDim.x + threadIdx.x;
    if (e >= 2 * NBONDS) return;
    int src, dst;
    if (e < NBONDS) { src = bf[e * 3 + 0]; dst = bf[e * 3 + 1]; }
    else { int i = e - NBONDS; src = bf[i * 3 + 1]; dst = bf[i * 3 + 0]; }
    esrc[e] = src;
    nxt[e] = atomicExch(&head[dst], e);
}

// ---------------------------------------------------------------------------
// Transpose W[rows][cols] -> Wt[cols][rows]
__global__ void transpose_kernel(const float* __restrict__ W, float* __restrict__ Wt,
                                 int rows, int cols) {
    int gid = blockIdx.x * blockDim.x + threadIdx.x;
    if (gid >= rows * cols) return;
    int n = gid / cols, k = gid % cols;
    Wt[k * rows + n] = W[gid];
}

__global__ void bsum_kernel(const float* __restrict__ a, const float* __restrict__ b,
                            float* __restrict__ o) {
    int i = threadIdx.x;
    o[i] = a[i] + b[i];
}

// ---------------------------------------------------------------------------
// Embedding: x[i][k] = sum_c emb[c][idx[i,c]][k]
__global__ void embed_kernel(const int* __restrict__ af, const float* __restrict__ emb,
                             float* __restrict__ x) {
    int gid = blockIdx.x * blockDim.x + threadIdx.x;
    int i = gid >> 5, k = gid & 31;
    if (i >= NATOMS) return;
    float s = 0.0f;
#pragma unroll
    for (int c = 0; c < NCOLS; c++) {
        int v = af[i * NCOLS + c];
        int idx = v & (VOCABSZ - 1);
        if (v >= 999999999) idx = 0;
        s += emb[((size_t)c * VOCABSZ + idx) * DCOL + k];
    }
    x[(size_t)i * DCOL + k] = s;
}

// ---------------------------------------------------------------------------
// Aggregation: agg[i][:] = sum over incoming edges of h[src][:]. One wave per atom.
__global__ void agg_kernel(const float* __restrict__ h, float* __restrict__ agg,
                           const int* __restrict__ head, const int* __restrict__ nxt,
                           const int* __restrict__ esrc) {
    int wid = (blockIdx.x * blockDim.x + threadIdx.x) >> 6;
    int lane = threadIdx.x & 63;
    if (wid >= NATOMS) return;
    float4 acc = make_float4(0.f, 0.f, 0.f, 0.f);
    int e = head[wid];
    while (e >= 0) {
        int src = esrc[e];
        float4 v = ((const float4*)(h + (size_t)src * HIDDIM))[lane];
        acc.x += v.x; acc.y += v.y; acc.z += v.z; acc.w += v.w;
        e = nxt[e];
    }
    ((float4*)(agg + (size_t)wid * HIDDIM))[lane] = acc;
}

// ---------------------------------------------------------------------------
// Fused GEMM: C = act(A1 @ W1t + [A2 @ W2t] + bias)
// A: [MP][K] row-major, Wt: [K][256] (pre-transposed), C: [MP][256]
// Block: 256 threads, tile 64(M) x 256(N), K chunked by 16.
// Thread (tm = t>>6, tn = t&63) computes rows tm*16..+15, cols 4*tn..+3.
template <bool HAS_A2, bool RELU>
__global__ __launch_bounds__(256, 2) void gemm_kernel(
    const float* __restrict__ A1, const float* __restrict__ A2,
    const float* __restrict__ W1t, const float* __restrict__ W2t,
    const float* __restrict__ bias, float* __restrict__ C, int K) {
    extern __shared__ float smem[];
    float* hs  = smem;                 // [16][68]  (stride 68: conflict-free staging)
    float* w1s = smem + 16 * 68;       // [16][256]
    float* as2 = w1s + 16 * 256;       // [16][68]   (HAS_A2 only)
    float* w2s = as2 + 16 * 68;        // [16][256]  (HAS_A2 only)

    const int t = threadIdx.x;
    const int tn = t & 63;
    const int tm = t >> 6;
    const int m0 = blockIdx.x * 64;
    const int ms = t >> 2;   // staging row 0..63
    const int js = t & 3;    // staging k-quad 0..3

    float acc[16][4];
#pragma unroll
    for (int m = 0; m < 16; m++) {
        acc[m][0] = 0.f; acc[m][1] = 0.f; acc[m][2] = 0.f; acc[m][3] = 0.f;
    }

    for (int k0 = 0; k0 < K; k0 += 16) {
        __syncthreads();
        {
            float4 v = *(const float4*)(A1 + (size_t)(m0 + ms) * K + k0 + 4 * js);
            hs[(4 * js + 0) * 68 + ms] = v.x;
            hs[(4 * js + 1) * 68 + ms] = v.y;
            hs[(4 * js + 2) * 68 + ms] = v.z;
            hs[(4 * js + 3) * 68 + ms] = v.w;
        }
        if (HAS_A2) {
            float4 v = *(const float4*)(A2 + (size_t)(m0 + ms) * K + k0 + 4 * js);
            as2[(4 * js + 0) * 68 + ms] = v.x;
            as2[(4 * js + 1) * 68 + ms] = v.y;
            as2[(4 * js + 2) * 68 + ms] = v.z;
            as2[(4 * js + 3) * 68 + ms] = v.w;
        }
        {
            const float4* src = (const float4*)(W1t + (size_t)k0 * HIDDIM);
            float4* dst = (float4*)w1s;
#pragma unroll
            for (int i = 0; i < 4; i++) dst[t + 256 * i] = src[t + 256 * i];
        }
        if (HAS_A2) {
            const float4* src = (const float4*)(W2t + (size_t)k0 * HIDDIM);
            float4* dst = (float4*)w2s;
#pragma unroll
            for (int i = 0; i < 4; i++) dst[t + 256 * i] = src[t + 256 * i];
        }
        __syncthreads();

#pragma unroll
        for (int kk = 0; kk < 16; kk++) {
            float4 w1 = *(const float4*)(w1s + kk * 256 + 4 * tn);
            float a[16];
#pragma unroll
            for (int q = 0; q < 4; q++)
                *(float4*)&a[4 * q] = *(const float4*)(hs + kk * 68 + tm * 16 + 4 * q);
            if (HAS_A2) {
                float4 w2 = *(const float4*)(w2s + kk * 256 + 4 * tn);
                float g[16];
#pragma unroll
                for (int q = 0; q < 4; q++)
                    *(float4*)&g[4 * q] = *(const float4*)(as2 + kk * 68 + tm * 16 + 4 * q);
#pragma unroll
                for (int m = 0; m < 16; m++) {
                    acc[m][0] += a[m] * w1.x + g[m] * w2.x;
                    acc[m][1] += a[m] * w1.y + g[m] * w2.y;
                    acc[m][2] += a[m] * w1.z + g[m] * w2.z;
                    acc[m][3] += a[m] * w1.w + g[m] * w2.w;
                }
            } else {
#pragma unroll
                for (int m = 0; m < 16; m++) {
                    acc[m][0] += a[m] * w1.x;
                    acc[m][1] += a[m] * w1.y;
                    acc[m][2] += a[m] * w1.z;
                    acc[m][3] += a[m] * w1.w;
                }
            }
        }
    }

    float4 b4 = *(const float4*)(bias + 4 * tn);
#pragma unroll
    for (int m = 0; m < 16; m++) {
        float4 o;
        o.x = acc[m][0] + b4.x;
        o.y = acc[m][1] + b4.y;
        o.z = acc[m][2] + b4.z;
        o.w = acc[m][3] + b4.w;
        if (RELU) {
            o.x = fmaxf(o.x, 0.f); o.y = fmaxf(o.y, 0.f);
            o.z = fmaxf(o.z, 0.f); o.w = fmaxf(o.w, 0.f);
        }
        *(float4*)(C + (size_t)(m0 + tm * 16 + m) * HIDDIM + 4 * tn) = o;
    }
}

// ---------------------------------------------------------------------------
// Readout: out[g][n] = mean over atoms in graph g
__global__ void readout_kernel(const float* __restrict__ h, const int* __restrict__ scopes,
                               float* __restrict__ out) {
    int g = blockIdx.x;
    int n = threadIdx.x;
    int start = scopes[g * 2 + 0];
    int len = scopes[g * 2 + 1];
    float s = 0.f;
    for (int j = 0; j < len; j++) s += h[(size_t)(start + j) * HIDDIM + n];
    int d = len > 1 ? len : 1;
    out[(size_t)g * HIDDIM + n] = s / (float)d;
}

// ---------------------------------------------------------------------------
extern "C" void kernel_launch(void* const* d_in, const int* in_sizes, int n_in,
                              void* d_out, int out_size, void* d_ws, size_t ws_size,
                              hipStream_t stream) {
    const int* a_features = (const int*)d_in[0];
    const int* b_features = (const int*)d_in[1];
    const int* a_scopes   = (const int*)d_in[2];
    const float* emb      = (const float*)d_in[3];
    const float* W_in     = (const float*)d_in[4];
    const float* b_in     = (const float*)d_in[5];
    const float* W_self   = (const float*)d_in[6];
    const float* b_self   = (const float*)d_in[7];
    const float* W_neigh  = (const float*)d_in[8];
    const float* b_neigh  = (const float*)d_in[9];
    const float* W_out    = (const float*)d_in[10];
    const float* b_out    = (const float*)d_in[11];

    if (g_pool == nullptr) {
        // debug marker: load-time hipMalloc failed
        fill_kernel<<<(out_size + 255) / 256, 256, 0, stream>>>(
            (float*)d_out, 77777.0f, out_size);
        return;
    }

    float* ws = (float*)g_pool;
    const size_t HBUF = (size_t)MP * HIDDIM;   // 76,808,192 floats
    float* bufA = ws;
    float* bufB = ws + HBUF;
    float* bufC = ws + 2 * HBUF;
    float* Wit  = ws + 3 * HBUF;               // [32][256]
    float* Wst  = Wit + (size_t)DCOL * HIDDIM; // [256][256]
    float* Wnt  = Wst + (size_t)HIDDIM * HIDDIM;
    float* Wot  = Wnt + (size_t)HIDDIM * HIDDIM;
    float* bsum = Wot + (size_t)HIDDIM * HIDDIM;
    int* esrc = (int*)(bsum + HIDDIM);
    int* nxt  = esrc + 2 * NBONDS;
    int* head = nxt + 2 * NBONDS;

    constexpr int SMEM_SMALL = (16 * 68 + 16 * HIDDIM) * 4;  // 20736 B
    constexpr int SMEM_BIG   = 2 * SMEM_SMALL;               // 41472 B
    constexpr int NPAD = MP - NATOMS;                        // 32 pad rows

    // --- setup (identical every launch) ---
    hipMemsetAsync(head, 0xFF, (size_t)MP * sizeof(int), stream);
    build_edges_kernel<<<(2 * NBONDS + 255) / 256, 256, 0, stream>>>(b_features, esrc, nxt, head);
    transpose_kernel<<<(HIDDIM * DCOL + 255) / 256, 256, 0, stream>>>(W_in, Wit, HIDDIM, DCOL);
    transpose_kernel<<<(HIDDIM * HIDDIM + 255) / 256, 256, 0, stream>>>(W_self, Wst, HIDDIM, HIDDIM);
    transpose_kernel<<<(HIDDIM * HIDDIM + 255) / 256, 256, 0, stream>>>(W_neigh, Wnt, HIDDIM, HIDDIM);
    transpose_kernel<<<(HIDDIM * HIDDIM + 255) / 256, 256, 0, stream>>>(W_out, Wot, HIDDIM, HIDDIM);
    bsum_kernel<<<1, HIDDIM, 0, stream>>>(b_self, b_neigh, bsum);

    // Zero the padding rows (pool is persistent, never harness-poisoned; keep
    // garbage/NaN out of the padded lanes deterministically).
    fill_kernel<<<(NPAD * HIDDIM + 255) / 256, 256, 0, stream>>>(bufA + (size_t)NATOMS * HIDDIM, 0.f, NPAD * HIDDIM);
    fill_kernel<<<(NPAD * HIDDIM + 255) / 256, 256, 0, stream>>>(bufB + (size_t)NATOMS * HIDDIM, 0.f, NPAD * HIDDIM);
    fill_kernel<<<(NPAD * HIDDIM + 255) / 256, 256, 0, stream>>>(bufC + (size_t)NATOMS * HIDDIM, 0.f, NPAD * HIDDIM);
    fill_kernel<<<(NPAD * DCOL + 255) / 256, 256, 0, stream>>>(bufB + (size_t)NATOMS * DCOL, 0.f, NPAD * DCOL);

    // --- embedding + input linear (x aliased into bufB, row stride DCOL) ---
    embed_kernel<<<(NATOMS * DCOL + 255) / 256, 256, 0, stream>>>(a_features, emb, bufB);
    gemm_kernel<false, false><<<GEMM_BLOCKS, 256, SMEM_SMALL, stream>>>(
        bufB, nullptr, Wit, nullptr, b_in, bufA, DCOL);

    // --- 3 message-passing steps with rotating buffers ---
    float* h  = bufA;
    float* ag = bufB;
    float* hn = bufC;
    for (int s = 0; s < NSTEPS; s++) {
        agg_kernel<<<NATOMS / 4, 256, 0, stream>>>(h, ag, head, nxt, esrc);
        gemm_kernel<true, true><<<GEMM_BLOCKS, 256, SMEM_BIG, stream>>>(
            h, ag, Wst, Wnt, bsum, hn, HIDDIM);
        float* oldh = h;
        h = hn; hn = ag; ag = oldh;
    }

    // --- output linear + readout ---
    gemm_kernel<false, false><<<GEMM_BLOCKS, 256, SMEM_SMALL, stream>>>(
        h, nullptr, Wot, nullptr, b_out, ag, HIDDIM);
    readout_kernel<<<NGRAPHS, 256, 0, stream>>>(ag, a_scopes, (float*)d_out);
}

// Round 3
// 4045.381 us; speedup vs baseline: 10.0776x; 10.0776x over previous
//
#include <hip/hip_runtime.h>

#define NATOMS 300000
#define NCOLS 8
#define VOCABSZ 4096
#define DCOL 32
#define HIDDIM 256
#define NBONDS 320000
#define NGRAPHS 6000
#define NSTEPS 3

constexpr int MP = 300032;            // atoms padded to multiple of 64
constexpr int GEMM_BLOCKS = MP / 64;  // 4688

// ---------------------------------------------------------------------------
// Global scratch pool, allocated ONCE at shared-library load time (dlopen),
// i.e. outside kernel_launch and outside any graph capture. kernel_launch
// performs identical work every call against this fixed pool.
static void* g_pool = nullptr;
__attribute__((constructor)) static void alloc_pool() {
    void* p = nullptr;
    if (hipMalloc(&p, (size_t)960 * 1024 * 1024) == hipSuccess) g_pool = p;
}

// ---------------------------------------------------------------------------
__global__ void fill_kernel(float* out, float v, int n) {
    int i = blockIdx.x * blockDim.x + threadIdx.x;
    if (i < n) out[i] = v;
}

// ---------------------------------------------------------------------------
// Build per-dst linked lists of directed edges (src = concat(u,v), dst = concat(v,u))
__global__ void build_edges_kernel(const int* __restrict__ bf, int* __restrict__ esrc,
                                   int* __restrict__ nxt, int* head) {
    int e = blockIdx.x * blockDim.x + threadIdx.x;
    if (e >= 2 * NBONDS) return;
    int src, dst;
    if (e < NBONDS) { src = bf[e * 3 + 0]; dst = bf[e * 3 + 1]; }
    else { int i = e - NBONDS; src = bf[i * 3 + 1]; dst = bf[i * 3 + 0]; }
    esrc[e] = src;
    nxt[e] = atomicExch(&head[dst], e);
}

// ---------------------------------------------------------------------------
// Transpose W[rows][cols] -> Wt[cols][rows]
__global__ void transpose_kernel(const float* __restrict__ W, float* __restrict__ Wt,
                                 int rows, int cols) {
    int gid = blockIdx.x * blockDim.x + threadIdx.x;
    if (gid >= rows * cols) return;
    int n = gid / cols, k = gid % cols;
    Wt[k * rows + n] = W[gid];
}

__global__ void bsum_kernel(const float* __restrict__ a, const float* __restrict__ b,
                            float* __restrict__ o) {
    int i = threadIdx.x;
    o[i] = a[i] + b[i];
}

// ---------------------------------------------------------------------------
// Embedding: x[i][k] = sum_c emb[c][idx[i,c]][k]
__global__ void embed_kernel(const int* __restrict__ af, const float* __restrict__ emb,
                             float* __restrict__ x) {
    int gid = blockIdx.x * blockDim.x + threadIdx.x;
    int i = gid >> 5, k = gid & 31;
    if (i >= NATOMS) return;
    float s = 0.0f;
#pragma unroll
    for (int c = 0; c < NCOLS; c++) {
        int v = af[i * NCOLS + c];
        int idx = v & (VOCABSZ - 1);
        if (v >= 999999999) idx = 0;
        s += emb[((size_t)c * VOCABSZ + idx) * DCOL + k];
    }
    x[(size_t)i * DCOL + k] = s;
}

// ---------------------------------------------------------------------------
// Aggregation: agg[i][:] = sum over incoming edges of h[src][:]. One wave per atom.
__global__ void agg_kernel(const float* __restrict__ h, float* __restrict__ agg,
                           const int* __restrict__ head, const int* __restrict__ nxt,
                           const int* __restrict__ esrc) {
    int wid = (blockIdx.x * blockDim.x + threadIdx.x) >> 6;
    int lane = threadIdx.x & 63;
    if (wid >= NATOMS) return;
    float4 acc = make_float4(0.f, 0.f, 0.f, 0.f);
    int e = head[wid];
    while (e >= 0) {
        int src = esrc[e];
        float4 v = ((const float4*)(h + (size_t)src * HIDDIM))[lane];
        acc.x += v.x; acc.y += v.y; acc.z += v.z; acc.w += v.w;
        e = nxt[e];
    }
    ((float4*)(agg + (size_t)wid * HIDDIM))[lane] = acc;
}

// ---------------------------------------------------------------------------
// Fused GEMM: C = act(A1 @ W1t + [A2 @ W2t] + bias)
// A: [MP][K] row-major, Wt: [K][256] (pre-transposed), C: [MP][256]
// Block: 256 threads, tile 64(M) x 256(N), K chunked by 16.
// Thread (tm = t>>6, tn = t&63) computes rows tm*16..+15, cols 4*tn..+3.
// NOTE: all inner-loop locals are float4 VALUES (no address-taken arrays) so
// nothing is demoted to scratch; acc[] is indexed only by unroll-constants.

#define FMA4(A, S, W)                       \
    A.x = fmaf((S), (W).x, A.x);            \
    A.y = fmaf((S), (W).y, A.y);            \
    A.z = fmaf((S), (W).z, A.z);            \
    A.w = fmaf((S), (W).w, A.w);

template <bool HAS_A2, bool RELU>
__global__ __launch_bounds__(256, 3) void gemm_kernel(
    const float* __restrict__ A1, const float* __restrict__ A2,
    const float* __restrict__ W1t, const float* __restrict__ W2t,
    const float* __restrict__ bias, float* __restrict__ C, int K) {
    extern __shared__ float smem[];
    float* hs  = smem;                 // [16][68]  (k-major, stride 68)
    float* w1s = smem + 16 * 68;       // [16][256]
    float* as2 = w1s + 16 * 256;       // [16][68]   (HAS_A2 only)
    float* w2s = as2 + 16 * 68;        // [16][256]  (HAS_A2 only)

    const int t = threadIdx.x;
    const int tn = t & 63;
    const int tm = t >> 6;
    const int m0 = blockIdx.x * 64;
    const int ms = t >> 2;   // staging row 0..63
    const int js = t & 3;    // staging k-quad 0..3

    float4 acc[16];
#pragma unroll
    for (int m = 0; m < 16; m++) acc[m] = make_float4(0.f, 0.f, 0.f, 0.f);

    for (int k0 = 0; k0 < K; k0 += 16) {
        __syncthreads();
        {
            float4 v = *(const float4*)(A1 + (size_t)(m0 + ms) * K + k0 + 4 * js);
            hs[(4 * js + 0) * 68 + ms] = v.x;
            hs[(4 * js + 1) * 68 + ms] = v.y;
            hs[(4 * js + 2) * 68 + ms] = v.z;
            hs[(4 * js + 3) * 68 + ms] = v.w;
        }
        if (HAS_A2) {
            float4 v = *(const float4*)(A2 + (size_t)(m0 + ms) * K + k0 + 4 * js);
            as2[(4 * js + 0) * 68 + ms] = v.x;
            as2[(4 * js + 1) * 68 + ms] = v.y;
            as2[(4 * js + 2) * 68 + ms] = v.z;
            as2[(4 * js + 3) * 68 + ms] = v.w;
        }
        {
            const float4* src = (const float4*)(W1t + (size_t)k0 * HIDDIM);
            float4* dst = (float4*)w1s;
#pragma unroll
            for (int i = 0; i < 4; i++) dst[t + 256 * i] = src[t + 256 * i];
        }
        if (HAS_A2) {
            const float4* src = (const float4*)(W2t + (size_t)k0 * HIDDIM);
            float4* dst = (float4*)w2s;
#pragma unroll
            for (int i = 0; i < 4; i++) dst[t + 256 * i] = src[t + 256 * i];
        }
        __syncthreads();

#pragma unroll
        for (int kk = 0; kk < 16; kk++) {
            const float4 w1 = *(const float4*)(w1s + kk * 256 + 4 * tn);
            const float4* ap = (const float4*)(hs + kk * 68 + tm * 16);
            if (HAS_A2) {
                const float4 w2 = *(const float4*)(w2s + kk * 256 + 4 * tn);
                const float4* gp = (const float4*)(as2 + kk * 68 + tm * 16);
#pragma unroll
                for (int q = 0; q < 4; q++) {
                    const float4 aq = ap[q];
                    const float4 gq = gp[q];
                    FMA4(acc[4 * q + 0], aq.x, w1); FMA4(acc[4 * q + 0], gq.x, w2);
                    FMA4(acc[4 * q + 1], aq.y, w1); FMA4(acc[4 * q + 1], gq.y, w2);
                    FMA4(acc[4 * q + 2], aq.z, w1); FMA4(acc[4 * q + 2], gq.z, w2);
                    FMA4(acc[4 * q + 3], aq.w, w1); FMA4(acc[4 * q + 3], gq.w, w2);
                }
            } else {
#pragma unroll
                for (int q = 0; q < 4; q++) {
                    const float4 aq = ap[q];
                    FMA4(acc[4 * q + 0], aq.x, w1);
                    FMA4(acc[4 * q + 1], aq.y, w1);
                    FMA4(acc[4 * q + 2], aq.z, w1);
                    FMA4(acc[4 * q + 3], aq.w, w1);
                }
            }
        }
    }

    const float4 b4 = *(const float4*)(bias + 4 * tn);
#pragma unroll
    for (int m = 0; m < 16; m++) {
        float4 o;
        o.x = acc[m].x + b4.x;
        o.y = acc[m].y + b4.y;
        o.z = acc[m].z + b4.z;
        o.w = acc[m].w + b4.w;
        if (RELU) {
            o.x = fmaxf(o.x, 0.f); o.y = fmaxf(o.y, 0.f);
            o.z = fmaxf(o.z, 0.f); o.w = fmaxf(o.w, 0.f);
        }
        *(float4*)(C + (size_t)(m0 + tm * 16 + m) * HIDDIM + 4 * tn) = o;
    }
}

// ---------------------------------------------------------------------------
// Readout: out[g][n] = mean over atoms in graph g
__global__ void readout_kernel(const float* __restrict__ h, const int* __restrict__ scopes,
                               float* __restrict__ out) {
    int g = blockIdx.x;
    int n = threadIdx.x;
    int start = scopes[g * 2 + 0];
    int len = scopes[g * 2 + 1];
    float s = 0.f;
    for (int j = 0; j < len; j++) s += h[(size_t)(start + j) * HIDDIM + n];
    int d = len > 1 ? len : 1;
    out[(size_t)g * HIDDIM + n] = s / (float)d;
}

// ---------------------------------------------------------------------------
extern "C" void kernel_launch(void* const* d_in, const int* in_sizes, int n_in,
                              void* d_out, int out_size, void* d_ws, size_t ws_size,
                              hipStream_t stream) {
    const int* a_features = (const int*)d_in[0];
    const int* b_features = (const int*)d_in[1];
    const int* a_scopes   = (const int*)d_in[2];
    const float* emb      = (const float*)d_in[3];
    const float* W_in     = (const float*)d_in[4];
    const float* b_in     = (const float*)d_in[5];
    const float* W_self   = (const float*)d_in[6];
    const float* b_self   = (const float*)d_in[7];
    const float* W_neigh  = (const float*)d_in[8];
    const float* b_neigh  = (const float*)d_in[9];
    const float* W_out    = (const float*)d_in[10];
    const float* b_out    = (const float*)d_in[11];

    if (g_pool == nullptr) {
        fill_kernel<<<(out_size + 255) / 256, 256, 0, stream>>>(
            (float*)d_out, 77777.0f, out_size);
        return;
    }

    float* ws = (float*)g_pool;
    const size_t HBUF = (size_t)MP * HIDDIM;   // 76,808,192 floats
    float* bufA = ws;
    float* bufB = ws + HBUF;
    float* bufC = ws + 2 * HBUF;
    float* Wit  = ws + 3 * HBUF;               // [32][256]
    float* Wst  = Wit + (size_t)DCOL * HIDDIM; // [256][256]
    float* Wnt  = Wst + (size_t)HIDDIM * HIDDIM;
    float* Wot  = Wnt + (size_t)HIDDIM * HIDDIM;
    float* bsum = Wot + (size_t)HIDDIM * HIDDIM;
    int* esrc = (int*)(bsum + HIDDIM);
    int* nxt  = esrc + 2 * NBONDS;
    int* head = nxt + 2 * NBONDS;

    constexpr int SMEM_SMALL = (16 * 68 + 16 * HIDDIM) * 4;  // 20736 B
    constexpr int SMEM_BIG   = 2 * SMEM_SMALL;               // 41472 B
    constexpr int NPAD = MP - NATOMS;                        // 32 pad rows

    // --- setup (identical every launch) ---
    hipMemsetAsync(head, 0xFF, (size_t)MP * sizeof(int), stream);
    build_edges_kernel<<<(2 * NBONDS + 255) / 256, 256, 0, stream>>>(b_features, esrc, nxt, head);
    transpose_kernel<<<(HIDDIM * DCOL + 255) / 256, 256, 0, stream>>>(W_in, Wit, HIDDIM, DCOL);
    transpose_kernel<<<(HIDDIM * HIDDIM + 255) / 256, 256, 0, stream>>>(W_self, Wst, HIDDIM, HIDDIM);
    transpose_kernel<<<(HIDDIM * HIDDIM + 255) / 256, 256, 0, stream>>>(W_neigh, Wnt, HIDDIM, HIDDIM);
    transpose_kernel<<<(HIDDIM * HIDDIM + 255) / 256, 256, 0, stream>>>(W_out, Wot, HIDDIM, HIDDIM);
    bsum_kernel<<<1, HIDDIM, 0, stream>>>(b_self, b_neigh, bsum);

    // Zero the padding rows (pool is persistent, never harness-poisoned).
    fill_kernel<<<(NPAD * HIDDIM + 255) / 256, 256, 0, stream>>>(bufA + (size_t)NATOMS * HIDDIM, 0.f, NPAD * HIDDIM);
    fill_kernel<<<(NPAD * HIDDIM + 255) / 256, 256, 0, stream>>>(bufB + (size_t)NATOMS * HIDDIM, 0.f, NPAD * HIDDIM);
    fill_kernel<<<(NPAD * HIDDIM + 255) / 256, 256, 0, stream>>>(bufC + (size_t)NATOMS * HIDDIM, 0.f, NPAD * HIDDIM);
    fill_kernel<<<(NPAD * DCOL + 255) / 256, 256, 0, stream>>>(bufB + (size_t)NATOMS * DCOL, 0.f, NPAD * DCOL);

    // --- embedding + input linear (x aliased into bufB, row stride DCOL) ---
    embed_kernel<<<(NATOMS * DCOL + 255) / 256, 256, 0, stream>>>(a_features, emb, bufB);
    gemm_kernel<false, false><<<GEMM_BLOCKS, 256, SMEM_SMALL, stream>>>(
        bufB, nullptr, Wit, nullptr, b_in, bufA, DCOL);

    // --- 3 message-passing steps with rotating buffers ---
    float* h  = bufA;
    float* ag = bufB;
    float* hn = bufC;
    for (int s = 0; s < NSTEPS; s++) {
        agg_kernel<<<NATOMS / 4, 256, 0, stream>>>(h, ag, head, nxt, esrc);
        gemm_kernel<true, true><<<GEMM_BLOCKS, 256, SMEM_BIG, stream>>>(
            h, ag, Wst, Wnt, bsum, hn, HIDDIM);
        float* oldh = h;
        h = hn; hn = ag; ag = oldh;
    }

    // --- output linear + readout ---
    gemm_kernel<false, false><<<GEMM_BLOCKS, 256, SMEM_SMALL, stream>>>(
        h, nullptr, Wot, nullptr, b_out, ag, HIDDIM);
    readout_kernel<<<NGRAPHS, 256, 0, stream>>>(ag, a_scopes, (float*)d_out);
}